// Round 1
// baseline (235.251 us; speedup 1.0000x reference)
//
#include <hip/hip_runtime.h>
#include <hip/hip_bf16.h>
#include <math.h>

#define N 1024
#define D 64
#define ALPHA 0.2f
#define LN_EPS 1e-5f
#define MASK_VAL -1000000000.0f

// ---------------------------------------------------------------------------
// Kernel 1: precompute row-wise projections.
//   Wh  = h @ W                      (N,64)
//   ei  = h @ E_i                    (N,64)   E_i = edge_w[:64]
//   ejB = h @ E_j + edge_b           (N,64)   E_j = edge_w[64:]
//   aj  = Wh @ A_j                   (N,64)   A_j = attn_w1[64:128]
//   aiB = Wh @ A_i + attn_b1         (N,64)   A_i = attn_w1[:64]
// grid 1024 x block 64 (one row per block, one output channel per thread)
// ---------------------------------------------------------------------------
__global__ __launch_bounds__(64) void gat_precompute(
    const float* __restrict__ h, const float* __restrict__ W,
    const float* __restrict__ attn_w1, const float* __restrict__ attn_b1,
    const float* __restrict__ edge_w, const float* __restrict__ edge_b,
    float* __restrict__ Wh, float* __restrict__ ejB, float* __restrict__ aj,
    float* __restrict__ ei, float* __restrict__ aiB)
{
    const int i = blockIdx.x;
    const int k = threadIdx.x;
    __shared__ float hrow[D];
    __shared__ float whrow[D];

    hrow[k] = h[i * D + k];
    __syncthreads();

    float wh = 0.f, vei = 0.f, vej = 0.f;
    #pragma unroll 8
    for (int m = 0; m < D; ++m) {
        float hm = hrow[m];
        wh  = fmaf(hm, W[m * D + k], wh);
        vei = fmaf(hm, edge_w[m * D + k], vei);
        vej = fmaf(hm, edge_w[(m + D) * D + k], vej);
    }
    Wh[i * D + k]  = wh;
    ei[i * D + k]  = vei;
    ejB[i * D + k] = vej + edge_b[k];
    whrow[k] = wh;
    __syncthreads();

    float vai = 0.f, vaj = 0.f;
    #pragma unroll 8
    for (int m = 0; m < D; ++m) {
        float wm = whrow[m];
        vai = fmaf(wm, attn_w1[m * D + k], vai);        // A_i rows 0..63
        vaj = fmaf(wm, attn_w1[(m + D) * D + k], vaj);  // A_j rows 64..127
    }
    aiB[i * D + k] = vai + attn_b1[k];
    aj[i * D + k]  = vaj;
}

__device__ __forceinline__ float leaky(float x) {
    return x > 0.f ? x : ALPHA * x;
}

// ---------------------------------------------------------------------------
// Kernel 2: fused per-row-i attention + aggregation + layernorm.
// One block per i (1024 blocks x 256 threads). Each thread owns j = c*256+tid.
// ---------------------------------------------------------------------------
__global__ __launch_bounds__(256) void gat_main(
    const float* __restrict__ h, const int* __restrict__ adj,
    const float* __restrict__ attn_w1, const float* __restrict__ attn_w2,
    const float* __restrict__ attn_b2,
    const float* __restrict__ ln_g, const float* __restrict__ ln_b,
    const float* __restrict__ Wh, const float* __restrict__ ejB,
    const float* __restrict__ aj, const float* __restrict__ ei,
    const float* __restrict__ aiB, float* __restrict__ out)
{
    const int i   = blockIdx.x;
    const int tid = threadIdx.x;
    const int lane = tid & 63;
    const int wid  = tid >> 6;
    const float* __restrict__ Ae = attn_w1 + 128 * D;   // A_e rows 128..191

    __shared__ float svec[D];     // ei[i,:]
    __shared__ float avec[D];     // aiB[i,:]  (attn_b1 folded in)
    __shared__ float w2s[D];
    __shared__ float e_lds[N];    // scores -> exp(scores)
    __shared__ float red[4 * D];  // per-wave-group partial h_prime
    __shared__ float sred[8];     // softmax reductions

    if (tid < D) {
        svec[tid] = ei[i * D + tid];
        avec[tid] = aiB[i * D + tid];
        w2s[tid]  = attn_w2[tid];
    }
    __syncthreads();
    const float b2 = attn_b2[0];

    // ------------- score computation: e[j] for j = tid, tid+256, ... -------
    for (int c = 0; c < N / 256; ++c) {
        const int j = c * 256 + tid;
        float acc[D];
        #pragma unroll
        for (int o = 0; o < D; ++o) acc[o] = 0.f;

        const float4* __restrict__ ejrow = (const float4*)(ejB + (size_t)j * D);
        for (int m4 = 0; m4 < D / 4; ++m4) {
            float4 v = ejrow[m4];
            float vv[4] = {v.x, v.y, v.z, v.w};
            #pragma unroll
            for (int q = 0; q < 4; ++q) {
                const int m = m4 * 4 + q;
                float ls = leaky(vv[q] + svec[m]);
                const float* __restrict__ aerow = Ae + m * D;  // wave-uniform
                #pragma unroll
                for (int o = 0; o < D; ++o)
                    acc[o] = fmaf(ls, aerow[o], acc[o]);
            }
        }

        // epilogue for this j: add ai+aj+b1, leaky, dot with w2
        const float4* __restrict__ ajrow = (const float4*)(aj + (size_t)j * D);
        float e = 0.f;
        for (int o4 = 0; o4 < D / 4; ++o4) {
            float4 a4 = ajrow[o4];
            float av[4] = {a4.x, a4.y, a4.z, a4.w};
            #pragma unroll
            for (int q = 0; q < 4; ++q) {
                const int o = o4 * 4 + q;
                float t = leaky(acc[o] + av[q] + avec[o]);
                e = fmaf(t, w2s[o], e);
            }
        }
        e += b2;
        if (adj[(size_t)i * N + j] == 0) e = MASK_VAL;
        e_lds[j] = e;
    }
    __syncthreads();

    // ------------- softmax over j -----------------------------------------
    float m = -INFINITY;
    for (int j = tid; j < N; j += 256) m = fmaxf(m, e_lds[j]);
    #pragma unroll
    for (int off = 32; off >= 1; off >>= 1) m = fmaxf(m, __shfl_xor(m, off, 64));
    if (lane == 0) sred[wid] = m;
    __syncthreads();
    m = fmaxf(fmaxf(sred[0], sred[1]), fmaxf(sred[2], sred[3]));

    float s = 0.f;
    for (int j = tid; j < N; j += 256) {
        float p = expf(e_lds[j] - m);
        e_lds[j] = p;   // each thread rewrites only its own entries
        s += p;
    }
    #pragma unroll
    for (int off = 32; off >= 1; off >>= 1) s += __shfl_xor(s, off, 64);
    if (lane == 0) sred[4 + wid] = s;
    __syncthreads();   // also publishes e_lds exp values to all threads
    const float inv_s = 1.f / (sred[4] + sred[5] + sred[6] + sred[7]);

    // ------------- h_prime = attention @ Wh + h ----------------------------
    // thread t: channel k = t&63, j-group g = t>>6 (256 j's per group)
    {
        const int k = lane, g = wid;
        float hp = 0.f;
        #pragma unroll 8
        for (int jj = 0; jj < 256; ++jj) {
            const int j = g * 256 + jj;
            hp = fmaf(e_lds[j], Wh[(size_t)j * D + k], hp);  // coalesced over k
        }
        red[g * D + k] = hp;
    }
    __syncthreads();

    // ------------- reduce + layernorm + store (wave 0 only) ----------------
    if (tid < D) {
        float v = (red[tid] + red[D + tid] + red[2 * D + tid] + red[3 * D + tid]) * inv_s
                  + h[(size_t)i * D + tid];
        float mu = v;
        #pragma unroll
        for (int off = 32; off >= 1; off >>= 1) mu += __shfl_xor(mu, off, 64);
        mu *= (1.f / D);
        float d = v - mu;
        float var = d * d;
        #pragma unroll
        for (int off = 32; off >= 1; off >>= 1) var += __shfl_xor(var, off, 64);
        var *= (1.f / D);
        float o = d * rsqrtf(var + LN_EPS) * ln_g[tid] + ln_b[tid];
        out[(size_t)i * D + tid] = o;
    }
}

// ---------------------------------------------------------------------------
extern "C" void kernel_launch(void* const* d_in, const int* in_sizes, int n_in,
                              void* d_out, int out_size, void* d_ws, size_t ws_size,
                              hipStream_t stream) {
    const float* h       = (const float*)d_in[0];
    const int*   adj     = (const int*)  d_in[1];
    const float* W       = (const float*)d_in[2];
    const float* attn_w1 = (const float*)d_in[3];
    const float* attn_b1 = (const float*)d_in[4];
    const float* attn_w2 = (const float*)d_in[5];
    const float* attn_b2 = (const float*)d_in[6];
    const float* edge_w  = (const float*)d_in[7];
    const float* edge_b  = (const float*)d_in[8];
    const float* ln_g    = (const float*)d_in[9];
    const float* ln_b    = (const float*)d_in[10];
    float* out = (float*)d_out;

    // workspace layout: 5 x (1024*64) f32 = 1.25 MB
    float* ws  = (float*)d_ws;
    float* Wh  = ws + 0 * (N * D);
    float* ejB = ws + 1 * (N * D);
    float* aj  = ws + 2 * (N * D);
    float* ei  = ws + 3 * (N * D);
    float* aiB = ws + 4 * (N * D);

    gat_precompute<<<N, 64, 0, stream>>>(h, W, attn_w1, attn_b1, edge_w, edge_b,
                                         Wh, ejB, aj, ei, aiB);
    gat_main<<<N, 256, 0, stream>>>(h, adj, attn_w1, attn_w2, attn_b2,
                                    ln_g, ln_b, Wh, ejB, aj, ei, aiB, out);
}

// Round 2
// 189.331 us; speedup vs baseline: 1.2425x; 1.2425x over previous
//
#include <hip/hip_runtime.h>
#include <math.h>

#define N 1024
#define D 64
#define ALPHA 0.2f
#define LN_EPS 1e-5f
#define MASK_VAL -1000000000.0f

typedef __attribute__((ext_vector_type(8))) short bf16x8;
typedef __attribute__((ext_vector_type(4))) float f32x4;

__device__ __forceinline__ float leaky(float x) { return fmaxf(x, ALPHA * x); }

// f32 -> bf16 round-to-nearest-even
__device__ __forceinline__ short f2bf(float f) {
    unsigned u = __builtin_bit_cast(unsigned, f);
    u += 0x7fffu + ((u >> 16) & 1u);
    return (short)(u >> 16);
}

// ---------------------------------------------------------------------------
// Kernel 1: row-wise projections. 4 rows per block (256 threads).
//   Wh  = h @ W ; ei = h @ E_i ; ejB = h @ E_j + edge_b
//   aj  = Wh @ A_j ; aiB = Wh @ A_i + attn_b1
// ---------------------------------------------------------------------------
__global__ __launch_bounds__(256) void gat_precompute(
    const float* __restrict__ h, const float* __restrict__ W,
    const float* __restrict__ attn_w1, const float* __restrict__ attn_b1,
    const float* __restrict__ edge_w, const float* __restrict__ edge_b,
    float* __restrict__ Wh, float* __restrict__ ejB, float* __restrict__ aj,
    float* __restrict__ ei, float* __restrict__ aiB)
{
    const int tid = threadIdx.x;
    const int r = tid >> 6;          // row within block
    const int k = tid & 63;
    const int i = blockIdx.x * 4 + r;
    __shared__ float hrow[4][D];
    __shared__ float whrow[4][D];

    hrow[r][k] = h[(size_t)i * D + k];
    __syncthreads();

    float wh = 0.f, vei = 0.f, vej = 0.f;
    #pragma unroll 8
    for (int m = 0; m < D; ++m) {
        float hm = hrow[r][m];
        wh  = fmaf(hm, W[m * D + k], wh);
        vei = fmaf(hm, edge_w[m * D + k], vei);
        vej = fmaf(hm, edge_w[(m + D) * D + k], vej);
    }
    Wh[(size_t)i * D + k]  = wh;
    ei[(size_t)i * D + k]  = vei;
    ejB[(size_t)i * D + k] = vej + edge_b[k];
    whrow[r][k] = wh;
    __syncthreads();

    float vai = 0.f, vaj = 0.f;
    #pragma unroll 8
    for (int m = 0; m < D; ++m) {
        float wm = whrow[r][m];
        vai = fmaf(wm, attn_w1[m * D + k], vai);        // A_i
        vaj = fmaf(wm, attn_w1[(m + D) * D + k], vaj);  // A_j
    }
    aiB[(size_t)i * D + k] = vai + attn_b1[k];
    aj[(size_t)i * D + k]  = vaj;
}

// ---------------------------------------------------------------------------
// Kernel 2: fused per-row-i attention (MFMA scores) + aggregation + LN.
// One block per i, 256 threads (4 waves). Wave w handles j in [w*256,(w+1)*256).
// Score GEMM: P = leaky(ei[i]+ejB[j]) @ A_e via mfma_f32_16x16x32_bf16.
// ---------------------------------------------------------------------------
__global__ __launch_bounds__(256) void gat_main(
    const float* __restrict__ h, const int* __restrict__ adj,
    const float* __restrict__ attn_w1, const float* __restrict__ attn_w2,
    const float* __restrict__ attn_b2,
    const float* __restrict__ ln_g, const float* __restrict__ ln_b,
    const float* __restrict__ Wh, const float* __restrict__ ejB,
    const float* __restrict__ aj, const float* __restrict__ ei,
    const float* __restrict__ aiB, float* __restrict__ out)
{
    const int i    = blockIdx.x;
    const int tid  = threadIdx.x;
    const int lane = tid & 63;
    const int wid  = tid >> 6;
    const int nloc = lane & 15;   // MFMA col (o dim) / A-row (j dim)
    const int quad = lane >> 4;
    const float* __restrict__ Ae = attn_w1 + 128 * D;   // A_e rows

    __shared__ __align__(16) float svec[D];   // ei[i,:]
    __shared__ __align__(16) float avec[D];   // aiB[i,:] (b1 folded)
    __shared__ __align__(16) float w2s[D];
    __shared__ float e_lds[N];
    __shared__ float red[4 * D];
    __shared__ float sred[8];

    if (tid < D) {
        svec[tid] = ei[(size_t)i * D + tid];
        avec[tid] = aiB[(size_t)i * D + tid];
        w2s[tid]  = attn_w2[tid];
    }
    __syncthreads();
    const float b2 = attn_b2[0];

    // --- B fragments: A_e in bf16, resident in VGPRs (per wave) -------------
    // B[k][n]: n = nloc, k = kt*32 + quad*8 + idx
    bf16x8 Bf[2][4];   // [kt][ot]
    #pragma unroll
    for (int kt = 0; kt < 2; ++kt)
        #pragma unroll
        for (int ot = 0; ot < 4; ++ot)
            #pragma unroll
            for (int idx = 0; idx < 8; ++idx) {
                int k = kt * 32 + quad * 8 + idx;
                Bf[kt][ot][idx] = f2bf(Ae[(size_t)k * D + ot * 16 + nloc]);
            }

    // per-lane epilogue constants
    float w2l[4], avl[4];
    #pragma unroll
    for (int ot = 0; ot < 4; ++ot) {
        w2l[ot] = w2s[ot * 16 + nloc];
        avl[ot] = avec[ot * 16 + nloc];
    }

    // --- score phase --------------------------------------------------------
    for (int g = 0; g < 4; ++g) {
        const int jbase = wid * 256 + g * 64;
        #pragma unroll
        for (int jt = 0; jt < 4; ++jt) {
            const int j = jbase + jt * 16 + nloc;
            const float* __restrict__ ejr = ejB + (size_t)j * D;

            // A fragment: A[m=nloc(j)][k = quad*8+idx (+32*kt)]
            bf16x8 Af[2];
            #pragma unroll
            for (int kt = 0; kt < 2; ++kt) {
                const int k0 = kt * 32 + quad * 8;
                float4 v0 = *(const float4*)(ejr + k0);
                float4 v1 = *(const float4*)(ejr + k0 + 4);
                float4 s0 = *(const float4*)(&svec[k0]);
                float4 s1 = *(const float4*)(&svec[k0 + 4]);
                Af[kt][0] = f2bf(leaky(v0.x + s0.x));
                Af[kt][1] = f2bf(leaky(v0.y + s0.y));
                Af[kt][2] = f2bf(leaky(v0.z + s0.z));
                Af[kt][3] = f2bf(leaky(v0.w + s0.w));
                Af[kt][4] = f2bf(leaky(v1.x + s1.x));
                Af[kt][5] = f2bf(leaky(v1.y + s1.y));
                Af[kt][6] = f2bf(leaky(v1.z + s1.z));
                Af[kt][7] = f2bf(leaky(v1.w + s1.w));
            }

            f32x4 acc[4] = {};
            #pragma unroll
            for (int ot = 0; ot < 4; ++ot) {
                acc[ot] = __builtin_amdgcn_mfma_f32_16x16x32_bf16(Af[0], Bf[0][ot], acc[ot], 0, 0, 0);
                acc[ot] = __builtin_amdgcn_mfma_f32_16x16x32_bf16(Af[1], Bf[1][ot], acc[ot], 0, 0, 0);
            }

            // epilogue: pre = P + aj[j] + aiB[i]; e = leaky(pre) . w2
            // lane holds rows j = jbase+jt*16+quad*4+r, col o = ot*16+nloc
            const int jr = jbase + jt * 16 + quad * 4;
            float part[4] = {0.f, 0.f, 0.f, 0.f};
            #pragma unroll
            for (int ot = 0; ot < 4; ++ot) {
                #pragma unroll
                for (int r = 0; r < 4; ++r) {
                    float pre = acc[ot][r] + aj[(size_t)(jr + r) * D + ot * 16 + nloc] + avl[ot];
                    part[r] = fmaf(leaky(pre), w2l[ot], part[r]);
                }
            }
            #pragma unroll
            for (int r = 0; r < 4; ++r) {
                float v = part[r];
                v += __shfl_xor(v, 1, 64);
                v += __shfl_xor(v, 2, 64);
                v += __shfl_xor(v, 4, 64);
                v += __shfl_xor(v, 8, 64);
                part[r] = v;
            }
            if (nloc == 0) {
                #pragma unroll
                for (int r = 0; r < 4; ++r)
                    e_lds[jr + r] = part[r] + b2;
            }
        }
    }
    __syncthreads();

    // --- mask + softmax -----------------------------------------------------
    float m = -INFINITY;
    #pragma unroll
    for (int c = 0; c < N / 256; ++c) {
        int j = c * 256 + tid;
        float raw = e_lds[j];
        if (adj[(size_t)i * N + j] == 0) raw = MASK_VAL;
        e_lds[j] = raw;
        m = fmaxf(m, raw);
    }
    #pragma unroll
    for (int off = 32; off >= 1; off >>= 1) m = fmaxf(m, __shfl_xor(m, off, 64));
    if (lane == 0) sred[wid] = m;
    __syncthreads();
    m = fmaxf(fmaxf(sred[0], sred[1]), fmaxf(sred[2], sred[3]));

    float s = 0.f;
    #pragma unroll
    for (int c = 0; c < N / 256; ++c) {
        int j = c * 256 + tid;
        float p = __expf(e_lds[j] - m);
        e_lds[j] = p;
        s += p;
    }
    #pragma unroll
    for (int off = 32; off >= 1; off >>= 1) s += __shfl_xor(s, off, 64);
    if (lane == 0) sred[4 + wid] = s;
    __syncthreads();
    const float inv_s = 1.f / (sred[4] + sred[5] + sred[6] + sred[7]);

    // --- h_prime = attention @ Wh + h --------------------------------------
    {
        const int k = lane, g = wid;
        float hp = 0.f;
        #pragma unroll 8
        for (int jj = 0; jj < 256; ++jj) {
            const int j = g * 256 + jj;
            hp = fmaf(e_lds[j], Wh[(size_t)j * D + k], hp);
        }
        red[g * D + k] = hp;
    }
    __syncthreads();

    // --- reduce + layernorm + store ----------------------------------------
    if (tid < D) {
        float v = (red[tid] + red[D + tid] + red[2 * D + tid] + red[3 * D + tid]) * inv_s
                  + h[(size_t)i * D + tid];
        float mu = v;
        #pragma unroll
        for (int off = 32; off >= 1; off >>= 1) mu += __shfl_xor(mu, off, 64);
        mu *= (1.f / D);
        float d = v - mu;
        float var = d * d;
        #pragma unroll
        for (int off = 32; off >= 1; off >>= 1) var += __shfl_xor(var, off, 64);
        var *= (1.f / D);
        float o = d * rsqrtf(var + LN_EPS) * ln_g[tid] + ln_b[tid];
        out[(size_t)i * D + tid] = o;
    }
}

// ---------------------------------------------------------------------------
extern "C" void kernel_launch(void* const* d_in, const int* in_sizes, int n_in,
                              void* d_out, int out_size, void* d_ws, size_t ws_size,
                              hipStream_t stream) {
    const float* h       = (const float*)d_in[0];
    const int*   adj     = (const int*)  d_in[1];
    const float* W       = (const float*)d_in[2];
    const float* attn_w1 = (const float*)d_in[3];
    const float* attn_b1 = (const float*)d_in[4];
    const float* attn_w2 = (const float*)d_in[5];
    const float* attn_b2 = (const float*)d_in[6];
    const float* edge_w  = (const float*)d_in[7];
    const float* edge_b  = (const float*)d_in[8];
    const float* ln_g    = (const float*)d_in[9];
    const float* ln_b    = (const float*)d_in[10];
    float* out = (float*)d_out;

    float* ws  = (float*)d_ws;
    float* Wh  = ws + 0 * (N * D);
    float* ejB = ws + 1 * (N * D);
    float* aj  = ws + 2 * (N * D);
    float* ei  = ws + 3 * (N * D);
    float* aiB = ws + 4 * (N * D);

    gat_precompute<<<N / 4, 256, 0, stream>>>(h, W, attn_w1, attn_b1, edge_w, edge_b,
                                              Wh, ejB, aj, ei, aiB);
    gat_main<<<N, 256, 0, stream>>>(h, adj, attn_w1, attn_w2, attn_b2,
                                    ln_g, ln_b, Wh, ejB, aj, ei, aiB, out);
}